// Round 4
// baseline (163.641 us; speedup 1.0000x reference)
//
#include <hip/hip_runtime.h>
#include <math.h>

// Problem constants (fixed by reference): B=32, T=2048, D=128
constexpr int B   = 32;
constexpr int T   = 2048;
constexpr int D   = 128;
constexpr int C   = 4;          // timesteps per thread (chunk)
constexpr int NCH = T / C;      // 512 chunks per sequence
constexpr int DG  = D / 4;      // 32 groups of 4 consecutive d per thread
constexpr int W   = 8;          // probe window (timesteps)

// R3: float4 ILP (R2) + full 524288-thread grid (R1's TLP). C=4, 4 d's per
// thread -> 2048 blocks (8/CU). Carry lookup is a vectorized window probe:
// load W=8 neighbor mask rows as int4 (independent -> 1 latency round), build
// per-j bitmasks, clz/ctz -> one dependent fetch. Loop windows only for
// unresolved j (P=2^-8 per window) -- no scalar serial path at all.
__global__ __launch_bounds__(256)
void linterp_kernel(const float* __restrict__ values,
                    const float* __restrict__ times,
                    const int*   __restrict__ mask,
                    float*       __restrict__ out)
{
    const int gid   = blockIdx.x * 256 + threadIdx.x;
    const int dg    = gid & (DG - 1);
    const int chunk = (gid >> 5) & (NCH - 1);   // DG = 2^5
    const int b     = gid >> 14;                // DG*NCH = 2^14

    const int d        = dg * 4;
    const int seq_base = b * T * D + d;         // element offset of (b,0,d)
    const int t0i      = chunk * C;

    // ---- load chunk into registers (12 independent dwordx4 loads) ----
    float4 xv[C], tmv[C], tlv[C];
    unsigned int mb[4] = {0u, 0u, 0u, 0u};
#pragma unroll
    for (int i = 0; i < C; ++i) {
        const int off = seq_base + (t0i + i) * D;
        xv[i]  = *(const float4*)(values + off);
        tmv[i] = *(const float4*)(times + off);
        const int4 m = *(const int4*)(mask + off);
        mb[0] |= (m.x != 0 ? 1u : 0u) << i;
        mb[1] |= (m.y != 0 ? 1u : 0u) << i;
        mb[2] |= (m.z != 0 ? 1u : 0u) << i;
        mb[3] |= (m.w != 0 ? 1u : 0u) << i;
    }

    // defaults for "no observation" match reference init values exactly:
    //   forward : x=0, t=times[b,0,d]      backward: x=0, t=times[b,T-1,d]
    const float4 t_first4 = *(const float4*)(times + seq_base);
    const float4 t_lastT4 = *(const float4*)(times + seq_base + (T - 1) * D);

    // ---- forward carry: last observed strictly before this chunk ----
    float fx[4] = {0.f, 0.f, 0.f, 0.f};
    float ft[4] = {t_first4.x, t_first4.y, t_first4.z, t_first4.w};
    {
        unsigned int unres = 0xFu;
        int hi = t0i;                               // exclusive upper bound
        while (unres && hi > 0) {
            const int lo = (hi >= W) ? hi - W : 0;
            unsigned int pb[4] = {0u, 0u, 0u, 0u};
#pragma unroll
            for (int i = 0; i < W; ++i) {
                const int t = lo + i;
                if (t < hi) {
                    const int4 m = *(const int4*)(mask + seq_base + t * D);
                    pb[0] |= (m.x != 0 ? 1u : 0u) << i;
                    pb[1] |= (m.y != 0 ? 1u : 0u) << i;
                    pb[2] |= (m.z != 0 ? 1u : 0u) << i;
                    pb[3] |= (m.w != 0 ? 1u : 0u) << i;
                }
            }
#pragma unroll
            for (int j = 0; j < 4; ++j) {
                if (((unres >> j) & 1u) && pb[j] != 0u) {
                    const int idx = 31 - __builtin_clz(pb[j]);  // latest observed
                    const int off = seq_base + (lo + idx) * D + j;
                    fx[j] = values[off]; ft[j] = times[off];
                    unres &= ~(1u << j);
                }
            }
            hi = lo;
        }
    }

    // ---- backward carry: first observed strictly after this chunk ----
    float bx[4] = {0.f, 0.f, 0.f, 0.f};
    float bt[4] = {t_lastT4.x, t_lastT4.y, t_lastT4.z, t_lastT4.w};
    {
        unsigned int unres = 0xFu;
        int lo = t0i + C;                           // inclusive lower bound
        while (unres && lo < T) {
            const int hi2 = (lo + W <= T) ? lo + W : T;
            unsigned int nb[4] = {0u, 0u, 0u, 0u};
#pragma unroll
            for (int i = 0; i < W; ++i) {
                const int t = lo + i;
                if (t < hi2) {
                    const int4 m = *(const int4*)(mask + seq_base + t * D);
                    nb[0] |= (m.x != 0 ? 1u : 0u) << i;
                    nb[1] |= (m.y != 0 ? 1u : 0u) << i;
                    nb[2] |= (m.z != 0 ? 1u : 0u) << i;
                    nb[3] |= (m.w != 0 ? 1u : 0u) << i;
                }
            }
#pragma unroll
            for (int j = 0; j < 4; ++j) {
                if (((unres >> j) & 1u) && nb[j] != 0u) {
                    const int idx = __builtin_ctz(nb[j]);       // earliest observed
                    const int off = seq_base + (lo + idx) * D + j;
                    bx[j] = values[off]; bt[j] = times[off];
                    unres &= ~(1u << j);
                }
            }
            lo = hi2;
        }
    }

    // ---- forward pass: x_last (in place of v) / t_last per element ----
#pragma unroll
    for (int i = 0; i < C; ++i) {
        float* xp = (float*)&xv[i];
        const float* tp = (const float*)&tmv[i];
        float* lp = (float*)&tlv[i];
#pragma unroll
        for (int j = 0; j < 4; ++j) {
            if ((mb[j] >> i) & 1u) { fx[j] = xp[j]; ft[j] = tp[j]; }
            xp[j] = fx[j];          // x_last overwrites v (equal when observed)
            lp[j] = ft[j];
        }
    }

    // ---- reverse pass: x_next/t_next on the fly, combine, store ----
#pragma unroll
    for (int i = C - 1; i >= 0; --i) {
        const float* xp = (const float*)&xv[i];
        const float* tp = (const float*)&tmv[i];
        const float* lp = (const float*)&tlv[i];
        float4 o;
        float* op = (float*)&o;
#pragma unroll
        for (int j = 0; j < 4; ++j) {
            const bool obs = (mb[j] >> i) & 1u;
            if (obs) { bx[j] = xp[j]; bt[j] = lp[j]; }  // == v[i], tm[i] when obs
            const float denom = bt[j] - lp[j];
            const float num   = xp[j] * (bt[j] - tp[j]) + bx[j] * (tp[j] - lp[j]);
            const bool  safe  = (denom != 0.f);
            float xi = num / (safe ? denom : 1.f);
            xi = (safe && isfinite(xi)) ? xi : 0.f;
            op[j] = obs ? xp[j] : xi;                   // xp[j]==v[i][j] when obs
        }
        *(float4*)(out + seq_base + (t0i + i) * D) = o;
    }
}

extern "C" void kernel_launch(void* const* d_in, const int* in_sizes, int n_in,
                              void* d_out, int out_size, void* d_ws, size_t ws_size,
                              hipStream_t stream)
{
    const float* values = (const float*)d_in[0];
    const float* times  = (const float*)d_in[1];
    const int*   mask   = (const int*)d_in[2];
    float*       out    = (float*)d_out;

    const int total_threads = B * NCH * DG;   // 524288 -> 2048 blocks
    linterp_kernel<<<total_threads / 256, 256, 0, stream>>>(values, times, mask, out);
}

// Round 5
// 149.985 us; speedup vs baseline: 1.0911x; 1.0911x over previous
//
#include <hip/hip_runtime.h>
#include <math.h>

// Problem constants (fixed by reference): B=32, T=2048, D=128
constexpr int B   = 32;
constexpr int T   = 2048;
constexpr int D   = 128;
constexpr int TB  = 32;          // output rows per block
constexpr int W   = 8;           // halo rows on each side
constexpr int RT  = TB + 2 * W;  // 48 rows spanned per block
constexpr int RG  = 8;           // row-groups (threads along time)
constexpr int RPT = RT / RG;     // 6 rows per thread
constexpr int DGN = 32;          // d-groups of 4 consecutive d
constexpr int NT  = T / TB;      // 64 tiles per sequence

// R4: block-cooperative. Block = (b, 32-row tile) x all 128 d. Each thread
// loads 6 rows x 4 d (v,t,m) incl. an 8-row halo each side -- ALL independent
// loads, one memory round. Threads reduce their rows to fwd/bwd (x,t)
// summaries in LDS; after one barrier each thread combines prefix/suffix
// summaries for its carry. No dependent global gather in the common path.
// Rare fallback (halo+prefix fully unobserved for a d): serial scalar probe.
// Sentinel: t < 0 means "no observation" (times = cumsum of U(0,1) > 0).
__global__ __launch_bounds__(256)
void linterp_kernel(const float* __restrict__ values,
                    const float* __restrict__ times,
                    const int*   __restrict__ mask,
                    float*       __restrict__ out)
{
    __shared__ float sFX[RG][D];   // fwd summary: x of LAST obs in row-group
    __shared__ float sFT[RG][D];   // fwd summary: t (or -1 if none)
    __shared__ float sBX[RG][D];   // bwd summary: x of FIRST obs in row-group
    __shared__ float sBT[RG][D];   // bwd summary: t (or -1 if none)

    const int tid  = threadIdx.x;
    const int dg   = tid & (DGN - 1);
    const int rg   = tid >> 5;
    const int tile = blockIdx.x & (NT - 1);
    const int b    = blockIdx.x >> 6;
    const int d    = dg * 4;
    const int base = b * T * D + d;
    const int tlo  = tile * TB;            // first output row
    const int row0 = tlo - W + rg * RPT;   // first row of this thread

    // ---- phase 1: load own rows (all independent, guarded for halo OOB) ----
    float4 v[RPT], tv[RPT];
    unsigned int mb[4] = {0u, 0u, 0u, 0u};
#pragma unroll
    for (int i = 0; i < RPT; ++i) {
        const int r = row0 + i;
        if (r >= 0 && r < T) {
            const int off = base + r * D;
            v[i]  = *(const float4*)(values + off);
            tv[i] = *(const float4*)(times + off);
            const int4 m = *(const int4*)(mask + off);
            mb[0] |= (m.x != 0 ? 1u : 0u) << i;
            mb[1] |= (m.y != 0 ? 1u : 0u) << i;
            mb[2] |= (m.z != 0 ? 1u : 0u) << i;
            mb[3] |= (m.w != 0 ? 1u : 0u) << i;
        } else {
            v[i]  = make_float4(0.f, 0.f, 0.f, 0.f);
            tv[i] = make_float4(0.f, 0.f, 0.f, 0.f);
        }
    }

    // defaults for globally-unobserved prefix/suffix (match reference init)
    const float4 tf4 = *(const float4*)(times + base);                 // row 0
    const float4 te4 = *(const float4*)(times + base + (T - 1) * D);   // row T-1

    // ---- local summaries per d: last obs (fwd) / first obs (bwd) ----
    {
        float fX[4], fT[4], bX[4], bT[4];
#pragma unroll
        for (int j = 0; j < 4; ++j) { fX[j] = 0.f; fT[j] = -1.f; bX[j] = 0.f; bT[j] = -1.f; }
#pragma unroll
        for (int i = 0; i < RPT; ++i) {
            const float* xp = (const float*)&v[i];
            const float* tp = (const float*)&tv[i];
#pragma unroll
            for (int j = 0; j < 4; ++j) {
                if ((mb[j] >> i) & 1u) {
                    fX[j] = xp[j]; fT[j] = tp[j];
                    if (bT[j] < 0.f) { bX[j] = xp[j]; bT[j] = tp[j]; }
                }
            }
        }
        *(float4*)&sFX[rg][d] = make_float4(fX[0], fX[1], fX[2], fX[3]);
        *(float4*)&sFT[rg][d] = make_float4(fT[0], fT[1], fT[2], fT[3]);
        *(float4*)&sBX[rg][d] = make_float4(bX[0], bX[1], bX[2], bX[3]);
        *(float4*)&sBT[rg][d] = make_float4(bT[0], bT[1], bT[2], bT[3]);
    }
    __syncthreads();

    const bool has_out = (rg >= 1) && (rg <= 6);   // rg0/rg7 are pure halo

    // ---- phase 2: combine prefix (fwd carry) / suffix (bwd carry) ----
    float cfX[4], cfT[4], cbX[4], cbT[4];
#pragma unroll
    for (int j = 0; j < 4; ++j) { cfX[j] = 0.f; cfT[j] = -1.f; cbX[j] = 0.f; cbT[j] = -1.f; }

    if (has_out) {
        for (int r2 = 0; r2 < rg; ++r2) {          // last valid wins
            const float4 px = *(const float4*)&sFX[r2][d];
            const float4 pt = *(const float4*)&sFT[r2][d];
            const float* pxp = (const float*)&px;
            const float* ptp = (const float*)&pt;
#pragma unroll
            for (int j = 0; j < 4; ++j)
                if (ptp[j] >= 0.f) { cfX[j] = pxp[j]; cfT[j] = ptp[j]; }
        }
        for (int r2 = RG - 1; r2 > rg; --r2) {     // first (lowest rg) wins
            const float4 nx = *(const float4*)&sBX[r2][d];
            const float4 nt = *(const float4*)&sBT[r2][d];
            const float* nxp = (const float*)&nx;
            const float* ntp = (const float*)&nt;
#pragma unroll
            for (int j = 0; j < 4; ++j)
                if (ntp[j] >= 0.f) { cbX[j] = nxp[j]; cbT[j] = ntp[j]; }
        }

        // ---- rare fallback: prefix (halo) fully unobserved for some d ----
#pragma unroll
        for (int j = 0; j < 4; ++j) {
            if (cfT[j] < 0.f) {
                for (int r = tlo - W - 1; r >= 0; --r) {           // serial, rare
                    const int off = base + r * D + j;
                    if (mask[off] != 0) { cfX[j] = values[off]; cfT[j] = times[off]; break; }
                }
                if (cfT[j] < 0.f) { cfX[j] = 0.f; cfT[j] = ((const float*)&tf4)[j]; }
            }
            if (cbT[j] < 0.f) {
                for (int r = tlo + TB + W; r < T; ++r) {           // serial, rare
                    const int off = base + r * D + j;
                    if (mask[off] != 0) { cbX[j] = values[off]; cbT[j] = times[off]; break; }
                }
                if (cbT[j] < 0.f) { cbX[j] = 0.f; cbT[j] = ((const float*)&te4)[j]; }
            }
        }

        // ---- phase 3: forward fill own rows (xl overwrites v; equal when obs) ----
        float4 tl[RPT];
#pragma unroll
        for (int i = 0; i < RPT; ++i) {
            float* xp = (float*)&v[i];
            const float* tp = (const float*)&tv[i];
            float* lp = (float*)&tl[i];
#pragma unroll
            for (int j = 0; j < 4; ++j) {
                if ((mb[j] >> i) & 1u) { cfX[j] = xp[j]; cfT[j] = tp[j]; }
                xp[j] = cfX[j];
                lp[j] = cfT[j];
            }
        }

        // ---- reverse: bwd fill + interpolate + store (output rows only) ----
#pragma unroll
        for (int i = RPT - 1; i >= 0; --i) {
            const int r = row0 + i;
            const float* xp = (const float*)&v[i];   // = x_last (== v when obs)
            const float* tp = (const float*)&tv[i];
            const float* lp = (const float*)&tl[i];
            float4 o;
            float* op = (float*)&o;
#pragma unroll
            for (int j = 0; j < 4; ++j) {
                const bool obs = (mb[j] >> i) & 1u;
                if (obs) { cbX[j] = xp[j]; cbT[j] = tp[j]; }
                const float denom = cbT[j] - lp[j];
                const float num   = xp[j] * (cbT[j] - tp[j]) + cbX[j] * (tp[j] - lp[j]);
                const bool  safe  = (denom != 0.f);
                float xi = num / (safe ? denom : 1.f);
                xi = (safe && isfinite(xi)) ? xi : 0.f;
                op[j] = obs ? xp[j] : xi;
            }
            if (r >= tlo && r < tlo + TB)
                *(float4*)(out + base + r * D) = o;
        }
    }
}

extern "C" void kernel_launch(void* const* d_in, const int* in_sizes, int n_in,
                              void* d_out, int out_size, void* d_ws, size_t ws_size,
                              hipStream_t stream)
{
    const float* values = (const float*)d_in[0];
    const float* times  = (const float*)d_in[1];
    const int*   mask   = (const int*)d_in[2];
    float*       out    = (float*)d_out;

    linterp_kernel<<<B * NT, 256, 0, stream>>>(values, times, mask, out);  // 2048 blocks
}